// Round 2
// baseline (1194.068 us; speedup 1.0000x reference)
//
#include <hip/hip_runtime.h>
#include <hip/hip_bf16.h>

typedef unsigned short u16;
typedef __attribute__((ext_vector_type(8))) short short8;   // 8 bf16 (4 VGPRs) — MFMA A/B frag
typedef __attribute__((ext_vector_type(4))) float floatx4;  // MFMA C/D frag

#define LN_EPS 1e-5f

__device__ __forceinline__ float bf2f(u16 u) {
    unsigned int i = ((unsigned int)u) << 16;
    float f; __builtin_memcpy(&f, &i, 4); return f;
}
__device__ __forceinline__ u16 f2bf(float f) {
    __hip_bfloat16 h = __float2bfloat16(f);   // RNE
    u16 u; __builtin_memcpy(&u, &h, 2); return u;
}

// ---------------------------------------------------------------- f32 -> f32 copy (x -> residual stream)
__global__ void copyf_kernel(const float* __restrict__ in, float* __restrict__ out, int n4) {
    int i = blockIdx.x * blockDim.x + threadIdx.x;
    if (i < n4) ((float4*)out)[i] = ((const float4*)in)[i];
}

// ---------------------------------------------------------------- f32 -> bf16 (weights)
__global__ void cvt_f2b_kernel(const float* __restrict__ in, u16* __restrict__ out, int n4) {
    int i = blockIdx.x * blockDim.x + threadIdx.x;
    if (i < n4) {
        float4 f = ((const float4*)in)[i];
        ((ushort4*)out)[i] = make_ushort4(f2bf(f.x), f2bf(f.y), f2bf(f.z), f2bf(f.w));
    }
}

// ---------------------------------------------------------------- LayerNorm over C=384, one wave per row, f32 in -> bf16 out
__global__ __launch_bounds__(64)
void ln_kernel(const float* __restrict__ xf, const float* __restrict__ g,
               const float* __restrict__ b, u16* __restrict__ out) {
    const int row = blockIdx.x;
    const int lane = threadIdx.x;
    const float* xr = xf + (size_t)row * 384;
    float v[6], s = 0.f, s2 = 0.f;
#pragma unroll
    for (int i = 0; i < 6; ++i) { v[i] = xr[lane + i * 64]; s += v[i]; s2 += v[i] * v[i]; }
#pragma unroll
    for (int off = 32; off; off >>= 1) { s += __shfl_xor(s, off); s2 += __shfl_xor(s2, off); }
    float mean = s * (1.0f / 384.0f);
    float var  = s2 * (1.0f / 384.0f) - mean * mean;
    float rstd = rsqrtf(var + LN_EPS);
    u16* orow = out + (size_t)row * 384;
#pragma unroll
    for (int i = 0; i < 6; ++i) {
        int c = lane + i * 64;
        orow[c] = f2bf((v[i] - mean) * rstd * g[c] + b[c]);
    }
}

// ---------------------------------------------------------------- MFMA NT GEMM: C[M,N] = A[M,K] * B[N,K]^T   (A,B bf16)
// ACONV: 0 = A plain [M,K]; 1 = implicit im2col of [B*2304, 384], H=W=48, K=3456, k=(dy*3+dx)*384+c
// EPI:   0 = store bf16; 1 = BN+GELU -> bf16; 2 = BN -> xf += gamma*val; 3 = xf += gamma*val
template<int ACONV, int EPI>
__global__ __launch_bounds__(256)
void gemm_nt(const u16* __restrict__ A, const u16* __restrict__ Bm,
             int M, int N, int K,
             u16* __restrict__ Obf, int ldo,
             float* __restrict__ xf,
             const float* __restrict__ bn_g, const float* __restrict__ bn_b,
             const float* __restrict__ bn_m, const float* __restrict__ bn_v,
             const float* __restrict__ gamma) {
    __shared__ u16 As[128][40];   // 32 k + 8 pad
    __shared__ u16 Bs[128][40];

    const int tid  = threadIdx.x;
    const int m0   = blockIdx.y * 128;
    const int n0   = blockIdx.x * 128;
    const int lane = tid & 63;
    const int wave = tid >> 6;
    const int wm   = (wave >> 1) * 64;
    const int wn   = (wave & 1) * 64;
    const int fr   = lane & 15;
    const int kq   = (lane >> 4) * 8;

    floatx4 acc[4][4];
#pragma unroll
    for (int i = 0; i < 4; ++i)
#pragma unroll
        for (int j = 0; j < 4; ++j) acc[i][j] = (floatx4){0.f, 0.f, 0.f, 0.f};

    for (int k0 = 0; k0 < K; k0 += 32) {
#pragma unroll
        for (int it = 0; it < 2; ++it) {
            int chunk = tid + it * 256;          // 0..511 : 128 rows x 4 chunks of 8 bf16
            int row = chunk >> 2;
            int kc  = (chunk & 3) * 8;
            uint4 av;
            if (ACONV == 0) {
                av = *(const uint4*)(A + (size_t)(m0 + row) * K + k0 + kc);
            } else {
                int rg = m0 + row;
                int b  = rg / 2304, n = rg - b * 2304;
                int y  = n / 48,    x = n - y * 48;
                int kg = k0 + kc;
                int j  = kg / 384,  c = kg - j * 384;
                int yy = y + j / 3 - 1;
                int xx = x + j % 3 - 1;
                if ((unsigned)yy < 48u && (unsigned)xx < 48u)
                    av = *(const uint4*)(A + ((size_t)(b * 2304 + yy * 48 + xx) * 384 + c));
                else
                    av = make_uint4(0u, 0u, 0u, 0u);
            }
            *(uint4*)(&As[row][kc]) = av;
            uint4 bv = *(const uint4*)(Bm + (size_t)(n0 + row) * K + k0 + kc);
            *(uint4*)(&Bs[row][kc]) = bv;
        }
        __syncthreads();

        short8 af[4], bfrag[4];
#pragma unroll
        for (int i = 0; i < 4; ++i) af[i]    = *(const short8*)(&As[wm + i * 16 + fr][kq]);
#pragma unroll
        for (int j = 0; j < 4; ++j) bfrag[j] = *(const short8*)(&Bs[wn + j * 16 + fr][kq]);
#pragma unroll
        for (int i = 0; i < 4; ++i)
#pragma unroll
            for (int j = 0; j < 4; ++j)
                acc[i][j] = __builtin_amdgcn_mfma_f32_16x16x32_bf16(af[i], bfrag[j], acc[i][j], 0, 0, 0);
        __syncthreads();
    }

    // Epilogue. C/D layout: col = lane&15, row = (lane>>4)*4 + reg   [verified m89/m91]
    const int quad4 = (lane >> 4) * 4;
#pragma unroll
    for (int j = 0; j < 4; ++j) {
        int col = n0 + wn + j * 16 + fr;
        float bscale = 0.f, bshift = 0.f, gam = 0.f;
        if (EPI == 1 || EPI == 2) {
            bscale = bn_g[col] * rsqrtf(bn_v[col] + LN_EPS);
            bshift = bn_b[col] - bn_m[col] * bscale;
        }
        if (EPI == 2 || EPI == 3) gam = gamma[col];
#pragma unroll
        for (int i = 0; i < 4; ++i) {
#pragma unroll
            for (int r = 0; r < 4; ++r) {
                int row = m0 + wm + i * 16 + quad4 + r;
                float v = acc[i][j][r];
                if (EPI == 0) {
                    Obf[(size_t)row * ldo + col] = f2bf(v);
                } else if (EPI == 1) {
                    float t = v * bscale + bshift;
                    t = 0.5f * t * (1.0f + erff(t * 0.70710678118654752f));
                    Obf[(size_t)row * ldo + col] = f2bf(t);
                } else if (EPI == 2) {
                    float t = v * bscale + bshift;
                    xf[(size_t)row * N + col] += gam * t;
                } else {
                    xf[(size_t)row * N + col] += gam * v;
                }
            }
        }
    }
}

// ---------------------------------------------------------------- channel attention: per (b,h) Gram + norms + softmax
__global__ __launch_bounds__(256)
void attn_kernel(const u16* __restrict__ qkv, const float* __restrict__ temp,
                 float* __restrict__ attnb) {
    const int bh = blockIdx.x;
    const int b = bh >> 3, h = bh & 7;
    const int tid = threadIdx.x;
    __shared__ float qsf[64][48];
    __shared__ float ksf[64][48];
    __shared__ float qns[48], kns[48];
    __shared__ float S[48][49];

    float acc9[3][3];
#pragma unroll
    for (int i = 0; i < 3; ++i)
#pragma unroll
        for (int j = 0; j < 3; ++j) acc9[i][j] = 0.f;
    float qn2 = 0.f, kn2 = 0.f;

    const int qoff = h * 48;
    const int koff = 384 + h * 48;
    const int d0 = (tid >> 4) * 3;
    const int e0 = (tid & 15) * 3;

    for (int n0 = 0; n0 < 2304; n0 += 64) {
#pragma unroll
        for (int it = 0; it < 6; ++it) {
            int chunk = tid + it * 256;          // 0..1535: [q 768 | k 768] chunks of 4 bf16
            int mat = chunk >= 768 ? 1 : 0;
            int rem = chunk - mat * 768;
            int nn = rem / 12, u = rem - nn * 12;
            ushort4 raw = *(const ushort4*)(qkv + (size_t)(b * 2304 + n0 + nn) * 1152 +
                                            (mat ? koff : qoff) + u * 4);
            float4 f = make_float4(bf2f(raw.x), bf2f(raw.y), bf2f(raw.z), bf2f(raw.w));
            if (mat) *(float4*)&ksf[nn][u * 4] = f;
            else     *(float4*)&qsf[nn][u * 4] = f;
        }
        __syncthreads();
#pragma unroll 4
        for (int nn = 0; nn < 64; ++nn) {
            float q0 = qsf[nn][d0], q1 = qsf[nn][d0 + 1], q2 = qsf[nn][d0 + 2];
            float k0v = ksf[nn][e0], k1v = ksf[nn][e0 + 1], k2v = ksf[nn][e0 + 2];
            acc9[0][0] += q0 * k0v; acc9[0][1] += q0 * k1v; acc9[0][2] += q0 * k2v;
            acc9[1][0] += q1 * k0v; acc9[1][1] += q1 * k1v; acc9[1][2] += q1 * k2v;
            acc9[2][0] += q2 * k0v; acc9[2][1] += q2 * k1v; acc9[2][2] += q2 * k2v;
        }
        if (tid < 48) {
            for (int nn = 0; nn < 64; ++nn) { float q = qsf[nn][tid]; qn2 += q * q; }
        } else if (tid >= 128 && tid < 176) {
            int e = tid - 128;
            for (int nn = 0; nn < 64; ++nn) { float k = ksf[nn][e]; kn2 += k * k; }
        }
        __syncthreads();
    }

    if (tid < 48) qns[tid] = fmaxf(sqrtf(qn2), 1e-12f);
    else if (tid >= 128 && tid < 176) kns[tid - 128] = fmaxf(sqrtf(kn2), 1e-12f);
    __syncthreads();

    float tf = temp[h];
#pragma unroll
    for (int i = 0; i < 3; ++i)
#pragma unroll
        for (int j = 0; j < 3; ++j)
            S[d0 + i][e0 + j] = acc9[i][j] * tf / (qns[d0 + i] * kns[e0 + j]);
    __syncthreads();

    if (tid < 48) {
        float mx = -1e30f;
        for (int e = 0; e < 48; ++e) mx = fmaxf(mx, S[tid][e]);
        float sum = 0.f;
        for (int e = 0; e < 48; ++e) { float t = __expf(S[tid][e] - mx); S[tid][e] = t; sum += t; }
        float inv = 1.0f / sum;
        float* dst = attnb + ((size_t)bh * 48 + tid) * 48;
        for (int e = 0; e < 48; ++e) dst[e] = S[tid][e] * inv;
    }
}

// ---------------------------------------------------------------- out[b,n,h*48+d] = sum_e attn[b,h,d,e] * v[b,n,h*48+e]
__global__ __launch_bounds__(256)
void attnout_kernel(const u16* __restrict__ qkv, const float* __restrict__ attnb,
                    u16* __restrict__ z) {
    const int r0 = blockIdx.x * 64;
    const int h  = blockIdx.y;
    const int b  = r0 / 2304;
    const int tid = threadIdx.x;
    __shared__ float A[48][49];
    __shared__ float vsf[64][48];

    const float* asrc = attnb + (size_t)(b * 8 + h) * 2304;
    for (int i = tid; i < 2304; i += 256) {
        int d = i / 48, e = i - d * 48;
        A[d][e] = asrc[i];
    }
    const int voff = 768 + h * 48;
    for (int i = tid; i < 768; i += 256) {      // 64 rows x 12 chunks of 4 bf16
        int nn = i / 12, u = i - nn * 12;
        ushort4 raw = *(const ushort4*)(qkv + (size_t)(r0 + nn) * 1152 + voff + u * 4);
        float4 f = make_float4(bf2f(raw.x), bf2f(raw.y), bf2f(raw.z), bf2f(raw.w));
        *(float4*)&vsf[nn][u * 4] = f;
    }
    __syncthreads();

    const int rr0 = (tid >> 4) * 4;
    const int d0  = (tid & 15) * 3;
    float acc[4][3];
#pragma unroll
    for (int r = 0; r < 4; ++r)
#pragma unroll
        for (int j = 0; j < 3; ++j) acc[r][j] = 0.f;

#pragma unroll 4
    for (int e = 0; e < 48; ++e) {
        float a0 = A[d0][e], a1 = A[d0 + 1][e], a2 = A[d0 + 2][e];
#pragma unroll
        for (int r = 0; r < 4; ++r) {
            float vv = vsf[rr0 + r][e];
            acc[r][0] += a0 * vv; acc[r][1] += a1 * vv; acc[r][2] += a2 * vv;
        }
    }
#pragma unroll
    for (int r = 0; r < 4; ++r)
#pragma unroll
        for (int j = 0; j < 3; ++j)
            z[(size_t)(r0 + rr0 + r) * 384 + h * 48 + d0 + j] = f2bf(acc[r][j]);
}

// ---------------------------------------------------------------- conv weight: f32 [O,C,3,3] -> bf16 [O, (dy*3+dx)*384 + c]
__global__ void reorder_w_kernel(const float* __restrict__ w, u16* __restrict__ wr, int n) {
    int i = blockIdx.x * blockDim.x + threadIdx.x;
    if (i < n) {
        int o = i / 3456, rem = i - o * 3456;
        int j = rem / 384, c = rem - j * 384;
        wr[i] = f2bf(w[(size_t)(o * 384 + c) * 9 + j]);
    }
}

// ---------------------------------------------------------------- final f32 store + (H, W) tail
__global__ void finalize_kernel(const float* __restrict__ xf, const int* __restrict__ Hp,
                                const int* __restrict__ Wp, float* __restrict__ out,
                                int n4, int n_extra) {
    int i = blockIdx.x * blockDim.x + threadIdx.x;
    if (i < n4) ((float4*)out)[i] = ((const float4*)xf)[i];
    if (i == 0) {
        size_t base = (size_t)n4 * 4;
        if (n_extra >= 1) out[base]     = (float)Hp[0];
        if (n_extra >= 2) out[base + 1] = (float)Wp[0];
    }
}

extern "C" void kernel_launch(void* const* d_in, const int* in_sizes, int n_in,
                              void* d_out, int out_size, void* d_ws, size_t ws_size,
                              hipStream_t stream) {
    const float* x      = (const float*)d_in[0];
    const float* ln1_g  = (const float*)d_in[1];
    const float* ln1_b  = (const float*)d_in[2];
    const float* w_qkv  = (const float*)d_in[3];
    const float* temp   = (const float*)d_in[4];
    const float* w_proj = (const float*)d_in[5];
    const float* gamma1 = (const float*)d_in[6];
    const float* ln2_g  = (const float*)d_in[7];
    const float* ln2_b  = (const float*)d_in[8];
    const float* mlp_w1 = (const float*)d_in[9];
    const float* bn1_g  = (const float*)d_in[10];
    const float* bn1_b  = (const float*)d_in[11];
    const float* bn1_m  = (const float*)d_in[12];
    const float* bn1_v  = (const float*)d_in[13];
    const float* mlp_w2 = (const float*)d_in[14];
    const float* bn2_g  = (const float*)d_in[15];
    const float* bn2_b  = (const float*)d_in[16];
    const float* bn2_m  = (const float*)d_in[17];
    const float* bn2_v  = (const float*)d_in[18];
    const float* gamma2 = (const float*)d_in[19];
    const float* ln3_g  = (const float*)d_in[20];
    const float* ln3_b  = (const float*)d_in[21];
    const float* pconv1 = (const float*)d_in[22];
    const float* pbn_g  = (const float*)d_in[23];
    const float* pbn_b  = (const float*)d_in[24];
    const float* pbn_m  = (const float*)d_in[25];
    const float* pbn_v  = (const float*)d_in[26];
    const float* pconv2 = (const float*)d_in[27];
    const float* gamma3 = (const float*)d_in[28];
    const int* Hp = (const int*)d_in[29];
    const int* Wp = (const int*)d_in[30];

    const int M = 36864, C = 384, C2 = 768, NQKV = 1152, KC = 3456;
    const size_t NBNC = (size_t)M * C;                 // 14,155,776

    const size_t SZ_XF  = NBNC * 4;                    //  56,623,104  f32 residual stream
    const size_t SZ_LN  = NBNC * 2;                    //  28,311,552  bf16 LN out / attn z
    const size_t SZ_BIG = (size_t)M * NQKV * 2;        //  84,934,656  bf16 qkv, later mlp hidden
    const size_t SZ_P3  = SZ_LN;                       //  28,311,552  attnb + bf16 weights, later conv1 out
    const size_t SZ_W   = (size_t)C * KC * 2;          //   2,654,208  per reordered conv weight
    if (ws_size < SZ_XF + SZ_LN + SZ_BIG + SZ_P3 + 2 * SZ_W) return;

    char* ws = (char*)d_ws;
    float* xf     = (float*)ws;
    u16*   lnbuf  = (u16*)(ws + SZ_XF);
    u16*   big    = (u16*)(ws + SZ_XF + SZ_LN);
    char*  p3     = ws + SZ_XF + SZ_LN + SZ_BIG;
    float* attnb  = (float*)p3;                                    // 1,179,648 B (128*48*48 f32)
    u16*   wqkvb  = (u16*)(p3 + 1179648);                          //   884,736 B
    u16*   wprojb = (u16*)(p3 + 1179648 + 884736);                 //   294,912 B
    u16*   w1b    = (u16*)(p3 + 1179648 + 884736 + 294912);        //   589,824 B
    u16*   w2b    = (u16*)(p3 + 1179648 + 884736 + 294912 + 589824); // 589,824 B (all dead before convbf)
    u16*   convbf = (u16*)p3;                                      // block-3 conv1 output (bf16, M*C)
    u16*   w1r    = (u16*)(p3 + SZ_P3);
    u16*   w2r    = (u16*)(p3 + SZ_P3 + SZ_W);

    const int n4 = (int)(NBNC / 4);
    const int n_extra = out_size - (int)NBNC;

    copyf_kernel<<<(n4 + 255) / 256, 256, 0, stream>>>(x, xf, n4);

    // weight conversions (f32 -> bf16)
    cvt_f2b_kernel<<<(NQKV * C / 4 + 255) / 256, 256, 0, stream>>>(w_qkv, wqkvb, NQKV * C / 4);
    cvt_f2b_kernel<<<(C * C / 4 + 255) / 256, 256, 0, stream>>>(w_proj, wprojb, C * C / 4);
    cvt_f2b_kernel<<<(C2 * C / 4 + 255) / 256, 256, 0, stream>>>(mlp_w1, w1b, C2 * C / 4);
    cvt_f2b_kernel<<<(C * C2 / 4 + 255) / 256, 256, 0, stream>>>(mlp_w2, w2b, C * C2 / 4);

    // --- attention block ---
    ln_kernel<<<M, 64, 0, stream>>>(xf, ln1_g, ln1_b, lnbuf);
    gemm_nt<0, 0><<<dim3(NQKV / 128, M / 128), 256, 0, stream>>>(
        lnbuf, wqkvb, M, NQKV, C, big, NQKV, nullptr, nullptr, nullptr, nullptr, nullptr, nullptr);
    attn_kernel<<<128, 256, 0, stream>>>(big, temp, attnb);
    attnout_kernel<<<dim3(M / 64, 8), 256, 0, stream>>>(big, attnb, lnbuf);
    gemm_nt<0, 3><<<dim3(C / 128, M / 128), 256, 0, stream>>>(
        lnbuf, wprojb, M, C, C, nullptr, 0, xf, nullptr, nullptr, nullptr, nullptr, gamma1);

    // --- ConvMlp block (1x1 convs + eval BN) ---
    ln_kernel<<<M, 64, 0, stream>>>(xf, ln2_g, ln2_b, lnbuf);
    gemm_nt<0, 1><<<dim3(C2 / 128, M / 128), 256, 0, stream>>>(
        lnbuf, w1b, M, C2, C, big, C2, nullptr, bn1_g, bn1_b, bn1_m, bn1_v, nullptr);
    gemm_nt<0, 2><<<dim3(C / 128, M / 128), 256, 0, stream>>>(
        big, w2b, M, C, C2, nullptr, 0, xf, bn2_g, bn2_b, bn2_m, bn2_v, gamma2);

    // --- projection block (3x3 conv -> BN -> GELU -> 3x3 conv), implicit im2col GEMMs ---
    ln_kernel<<<M, 64, 0, stream>>>(xf, ln3_g, ln3_b, lnbuf);
    reorder_w_kernel<<<(C * KC + 255) / 256, 256, 0, stream>>>(pconv1, w1r, C * KC);
    reorder_w_kernel<<<(C * KC + 255) / 256, 256, 0, stream>>>(pconv2, w2r, C * KC);
    gemm_nt<1, 1><<<dim3(C / 128, M / 128), 256, 0, stream>>>(
        lnbuf, w1r, M, C, KC, convbf, C, nullptr, pbn_g, pbn_b, pbn_m, pbn_v, nullptr);
    gemm_nt<1, 3><<<dim3(C / 128, M / 128), 256, 0, stream>>>(
        convbf, w2r, M, C, KC, nullptr, 0, xf, nullptr, nullptr, nullptr, nullptr, gamma3);

    finalize_kernel<<<(n4 + 255) / 256, 256, 0, stream>>>(xf, Hp, Wp, (float*)d_out, n4, n_extra);
}

// Round 3
// 1025.029 us; speedup vs baseline: 1.1649x; 1.1649x over previous
//
#include <hip/hip_runtime.h>
#include <hip/hip_bf16.h>

typedef unsigned short u16;
typedef __attribute__((ext_vector_type(8))) short short8;   // 8 bf16 (4 VGPRs) — MFMA A/B frag
typedef __attribute__((ext_vector_type(4))) float floatx4;  // MFMA C/D frag

#define LN_EPS 1e-5f

__device__ __forceinline__ float bf2f(u16 u) {
    unsigned int i = ((unsigned int)u) << 16;
    float f; __builtin_memcpy(&f, &i, 4); return f;
}
__device__ __forceinline__ u16 f2bf(float f) {
    __hip_bfloat16 h = __float2bfloat16(f);   // RNE
    u16 u; __builtin_memcpy(&u, &h, 2); return u;
}

// async global->LDS, 16 B per lane; lds dest must be wave-uniform (HW adds lane*16)
__device__ __forceinline__ void gl_lds16(const u16* g, u16* l) {
    __builtin_amdgcn_global_load_lds(
        (const __attribute__((address_space(1))) void*)(const void*)g,
        (__attribute__((address_space(3))) void*)(void*)l,
        16, 0, 0);
}

// ---------------------------------------------------------------- f32 -> f32 copy (x -> residual stream)
__global__ void copyf_kernel(const float* __restrict__ in, float* __restrict__ out, int n4) {
    int i = blockIdx.x * blockDim.x + threadIdx.x;
    if (i < n4) ((float4*)out)[i] = ((const float4*)in)[i];
}

// ---------------------------------------------------------------- f32 -> bf16 (weights)
__global__ void cvt_f2b_kernel(const float* __restrict__ in, u16* __restrict__ out, int n4) {
    int i = blockIdx.x * blockDim.x + threadIdx.x;
    if (i < n4) {
        float4 f = ((const float4*)in)[i];
        ((ushort4*)out)[i] = make_ushort4(f2bf(f.x), f2bf(f.y), f2bf(f.z), f2bf(f.w));
    }
}

__global__ void zero_kernel(u16* __restrict__ p, int n) {
    int i = blockIdx.x * blockDim.x + threadIdx.x;
    if (i < n) p[i] = 0;
}

// ---------------------------------------------------------------- LayerNorm over C=384, one wave per row
__global__ __launch_bounds__(64)
void ln_kernel(const float* __restrict__ xf, const float* __restrict__ g,
               const float* __restrict__ b, u16* __restrict__ out) {
    const int row = blockIdx.x;
    const int lane = threadIdx.x;
    const float* xr = xf + (size_t)row * 384;
    float v[6], s = 0.f, s2 = 0.f;
#pragma unroll
    for (int i = 0; i < 6; ++i) { v[i] = xr[lane + i * 64]; s += v[i]; s2 += v[i] * v[i]; }
#pragma unroll
    for (int off = 32; off; off >>= 1) { s += __shfl_xor(s, off); s2 += __shfl_xor(s2, off); }
    float mean = s * (1.0f / 384.0f);
    float var  = s2 * (1.0f / 384.0f) - mean * mean;
    float rstd = rsqrtf(var + LN_EPS);
    u16* orow = out + (size_t)row * 384;
#pragma unroll
    for (int i = 0; i < 6; ++i) {
        int c = lane + i * 64;
        orow[c] = f2bf((v[i] - mean) * rstd * g[c] + b[c]);
    }
}

// ---------------------------------------------------------------- MFMA NT GEMM: C[M,N] = A[M,K] * B[N,K]^T   (A,B bf16)
// ACONV: 0 = A plain [M,K]; 1 = implicit im2col of [B*2304, 384], H=W=48, K=3456, k=(dy*3+dx)*384+c
// EPI:   0 = store bf16; 1 = BN+GELU -> bf16; 2 = BN -> xf += gamma*val; 3 = xf += gamma*val;
//        4 = ofb = xf + gamma*val (f32 out, fused finalize)
template<int ACONV, int EPI>
__global__ __launch_bounds__(256)
void gemm_nt(const u16* __restrict__ A, const u16* __restrict__ Bm,
             int M, int N, int K,
             u16* __restrict__ Obf, int ldo,
             float* __restrict__ xf, float* __restrict__ ofb,
             const float* __restrict__ bn_g, const float* __restrict__ bn_b,
             const float* __restrict__ bn_m, const float* __restrict__ bn_v,
             const float* __restrict__ gamma, const u16* __restrict__ zp) {
    __shared__ u16 As[128 * 32];   // unpadded: chunk-contiguous for global_load_lds
    __shared__ u16 Bs[128 * 32];

    const int tid  = threadIdx.x;
    const int m0   = blockIdx.y * 128;
    const int n0   = blockIdx.x * 128;
    const int lane = tid & 63;
    const int wave = tid >> 6;
    const int wm   = (wave >> 1) * 64;
    const int wn   = (wave & 1) * 64;
    const int fr   = lane & 15;
    const int kq   = (lane >> 4) * 8;

    // staging geometry: chunk = it*256 + tid ; row = chunk>>2 ; kc = (chunk&3)*8
    const int row0 = tid >> 2;             // it=0 row; it=1 row = row0+64
    const int kc0  = (tid & 3) * 8;
    u16* ldsA0 = As + wave * 512;          // wave-uniform bases (64 lanes x 8 u16)
    u16* ldsA1 = As + 2048 + wave * 512;
    u16* ldsB0 = Bs + wave * 512;
    u16* ldsB1 = Bs + 2048 + wave * 512;

    floatx4 acc[4][4];
#pragma unroll
    for (int i = 0; i < 4; ++i)
#pragma unroll
        for (int j = 0; j < 4; ++j) acc[i][j] = (floatx4){0.f, 0.f, 0.f, 0.f};

#define MFMA_TILE()                                                                 \
    do {                                                                            \
        short8 af[4], bfr[4];                                                       \
        _Pragma("unroll")                                                           \
        for (int i = 0; i < 4; ++i)                                                 \
            af[i] = *(const short8*)(&As[(wm + i * 16 + fr) * 32 + kq]);            \
        _Pragma("unroll")                                                           \
        for (int j = 0; j < 4; ++j)                                                 \
            bfr[j] = *(const short8*)(&Bs[(wn + j * 16 + fr) * 32 + kq]);           \
        _Pragma("unroll")                                                           \
        for (int i = 0; i < 4; ++i)                                                 \
            _Pragma("unroll")                                                       \
            for (int j = 0; j < 4; ++j)                                             \
                acc[i][j] = __builtin_amdgcn_mfma_f32_16x16x32_bf16(af[i], bfr[j],  \
                                                                    acc[i][j], 0, 0, 0); \
    } while (0)

    if (ACONV == 0) {
        const u16* a0 = A + (size_t)(m0 + row0) * K + kc0;
        const u16* a1 = A + (size_t)(m0 + row0 + 64) * K + kc0;
        const u16* b0 = Bm + (size_t)(n0 + row0) * K + kc0;
        const u16* b1 = Bm + (size_t)(n0 + row0 + 64) * K + kc0;
        for (int k0 = 0; k0 < K; k0 += 32) {
            gl_lds16(a0, ldsA0); gl_lds16(a1, ldsA1);
            gl_lds16(b0, ldsB0); gl_lds16(b1, ldsB1);
            a0 += 32; a1 += 32; b0 += 32; b1 += 32;
            __syncthreads();
            MFMA_TILE();
            __syncthreads();
        }
    } else {
        const int bimg = m0 / 2304;
        const int nb   = m0 - bimg * 2304;
        const int nA   = nb + row0;
        const int y0 = nA / 48,        x0 = nA - y0 * 48;
        const int y1 = (nA + 64) / 48, x1 = (nA + 64) - ((nA + 64) / 48) * 48;
        const u16* img = A + (size_t)bimg * 2304 * 384;
        const u16* b0 = Bm + (size_t)(n0 + row0) * K + kc0;
        const u16* b1 = Bm + (size_t)(n0 + row0 + 64) * K + kc0;
        for (int j = 0; j < 9; ++j) {
            const int dy = j / 3 - 1, dx = j % 3 - 1;
            const int yy0 = y0 + dy, xx0 = x0 + dx;
            const int yy1 = y1 + dy, xx1 = x1 + dx;
            const bool v0 = ((unsigned)yy0 < 48u) & ((unsigned)xx0 < 48u);
            const bool v1 = ((unsigned)yy1 < 48u) & ((unsigned)xx1 < 48u);
            const u16* a0 = v0 ? img + (size_t)(yy0 * 48 + xx0) * 384 + kc0 : zp;
            const u16* a1 = v1 ? img + (size_t)(yy1 * 48 + xx1) * 384 + kc0 : zp;
            for (int c0 = 0; c0 < 384; c0 += 32) {
                gl_lds16(a0, ldsA0); gl_lds16(a1, ldsA1);
                gl_lds16(b0, ldsB0); gl_lds16(b1, ldsB1);
                a0 += 32; a1 += 32; b0 += 32; b1 += 32;   // zp page is 4 KB zeros: a+352+8 stays inside
                __syncthreads();
                MFMA_TILE();
                __syncthreads();
            }
        }
    }
#undef MFMA_TILE

    // Epilogue. C/D layout: col = lane&15, row = (lane>>4)*4 + reg   [verified m89/m91]
    const int quad4 = (lane >> 4) * 4;
#pragma unroll
    for (int j = 0; j < 4; ++j) {
        int col = n0 + wn + j * 16 + fr;
        float bscale = 0.f, bshift = 0.f, gam = 0.f;
        if (EPI == 1 || EPI == 2) {
            bscale = bn_g[col] * rsqrtf(bn_v[col] + LN_EPS);
            bshift = bn_b[col] - bn_m[col] * bscale;
        }
        if (EPI == 2 || EPI == 3 || EPI == 4) gam = gamma[col];
#pragma unroll
        for (int i = 0; i < 4; ++i) {
#pragma unroll
            for (int r = 0; r < 4; ++r) {
                int row = m0 + wm + i * 16 + quad4 + r;
                float v = acc[i][j][r];
                if (EPI == 0) {
                    Obf[(size_t)row * ldo + col] = f2bf(v);
                } else if (EPI == 1) {
                    float t = v * bscale + bshift;
                    t = 0.5f * t * (1.0f + erff(t * 0.70710678118654752f));
                    Obf[(size_t)row * ldo + col] = f2bf(t);
                } else if (EPI == 2) {
                    float t = v * bscale + bshift;
                    xf[(size_t)row * N + col] += gam * t;
                } else if (EPI == 3) {
                    xf[(size_t)row * N + col] += gam * v;
                } else {
                    ofb[(size_t)row * N + col] = xf[(size_t)row * N + col] + gam * v;
                }
            }
        }
    }
}

// ---------------------------------------------------------------- channel attention: per (b,h) Gram + norms + softmax
__global__ __launch_bounds__(256)
void attn_kernel(const u16* __restrict__ qkv, const float* __restrict__ temp,
                 float* __restrict__ attnb) {
    const int bh = blockIdx.x;
    const int b = bh >> 3, h = bh & 7;
    const int tid = threadIdx.x;
    __shared__ float qsf[64][48];
    __shared__ float ksf[64][48];
    __shared__ float qns[48], kns[48];
    __shared__ float S[48][49];

    float acc9[3][3];
#pragma unroll
    for (int i = 0; i < 3; ++i)
#pragma unroll
        for (int j = 0; j < 3; ++j) acc9[i][j] = 0.f;
    float qn2 = 0.f, kn2 = 0.f;

    const int qoff = h * 48;
    const int koff = 384 + h * 48;
    const int d0 = (tid >> 4) * 3;
    const int e0 = (tid & 15) * 3;

    for (int n0 = 0; n0 < 2304; n0 += 64) {
#pragma unroll
        for (int it = 0; it < 6; ++it) {
            int chunk = tid + it * 256;          // 0..1535: [q 768 | k 768] chunks of 4 bf16
            int mat = chunk >= 768 ? 1 : 0;
            int rem = chunk - mat * 768;
            int nn = rem / 12, u = rem - nn * 12;
            ushort4 raw = *(const ushort4*)(qkv + (size_t)(b * 2304 + n0 + nn) * 1152 +
                                            (mat ? koff : qoff) + u * 4);
            float4 f = make_float4(bf2f(raw.x), bf2f(raw.y), bf2f(raw.z), bf2f(raw.w));
            if (mat) *(float4*)&ksf[nn][u * 4] = f;
            else     *(float4*)&qsf[nn][u * 4] = f;
        }
        __syncthreads();
#pragma unroll 4
        for (int nn = 0; nn < 64; ++nn) {
            float q0 = qsf[nn][d0], q1 = qsf[nn][d0 + 1], q2 = qsf[nn][d0 + 2];
            float k0v = ksf[nn][e0], k1v = ksf[nn][e0 + 1], k2v = ksf[nn][e0 + 2];
            acc9[0][0] += q0 * k0v; acc9[0][1] += q0 * k1v; acc9[0][2] += q0 * k2v;
            acc9[1][0] += q1 * k0v; acc9[1][1] += q1 * k1v; acc9[1][2] += q1 * k2v;
            acc9[2][0] += q2 * k0v; acc9[2][1] += q2 * k1v; acc9[2][2] += q2 * k2v;
        }
        if (tid < 48) {
            for (int nn = 0; nn < 64; ++nn) { float q = qsf[nn][tid]; qn2 += q * q; }
        } else if (tid >= 128 && tid < 176) {
            int e = tid - 128;
            for (int nn = 0; nn < 64; ++nn) { float k = ksf[nn][e]; kn2 += k * k; }
        }
        __syncthreads();
    }

    if (tid < 48) qns[tid] = fmaxf(sqrtf(qn2), 1e-12f);
    else if (tid >= 128 && tid < 176) kns[tid - 128] = fmaxf(sqrtf(kn2), 1e-12f);
    __syncthreads();

    float tf = temp[h];
#pragma unroll
    for (int i = 0; i < 3; ++i)
#pragma unroll
        for (int j = 0; j < 3; ++j)
            S[d0 + i][e0 + j] = acc9[i][j] * tf / (qns[d0 + i] * kns[e0 + j]);
    __syncthreads();

    if (tid < 48) {
        float mx = -1e30f;
        for (int e = 0; e < 48; ++e) mx = fmaxf(mx, S[tid][e]);
        float sum = 0.f;
        for (int e = 0; e < 48; ++e) { float t = __expf(S[tid][e] - mx); S[tid][e] = t; sum += t; }
        float inv = 1.0f / sum;
        float* dst = attnb + ((size_t)bh * 48 + tid) * 48;
        for (int e = 0; e < 48; ++e) dst[e] = S[tid][e] * inv;
    }
}

// ---------------------------------------------------------------- out[b,n,h*48+d] = sum_e attn[b,h,d,e] * v[b,n,h*48+e]
__global__ __launch_bounds__(256)
void attnout_kernel(const u16* __restrict__ qkv, const float* __restrict__ attnb,
                    u16* __restrict__ z) {
    const int r0 = blockIdx.x * 64;
    const int h  = blockIdx.y;
    const int b  = r0 / 2304;
    const int tid = threadIdx.x;
    __shared__ float A[48][49];
    __shared__ float vsf[64][48];

    const float* asrc = attnb + (size_t)(b * 8 + h) * 2304;
    for (int i = tid; i < 2304; i += 256) {
        int d = i / 48, e = i - d * 48;
        A[d][e] = asrc[i];
    }
    const int voff = 768 + h * 48;
    for (int i = tid; i < 768; i += 256) {
        int nn = i / 12, u = i - nn * 12;
        ushort4 raw = *(const ushort4*)(qkv + (size_t)(r0 + nn) * 1152 + voff + u * 4);
        float4 f = make_float4(bf2f(raw.x), bf2f(raw.y), bf2f(raw.z), bf2f(raw.w));
        *(float4*)&vsf[nn][u * 4] = f;
    }
    __syncthreads();

    const int rr0 = (tid >> 4) * 4;
    const int d0  = (tid & 15) * 3;
    float acc[4][3];
#pragma unroll
    for (int r = 0; r < 4; ++r)
#pragma unroll
        for (int j = 0; j < 3; ++j) acc[r][j] = 0.f;

#pragma unroll 4
    for (int e = 0; e < 48; ++e) {
        float a0 = A[d0][e], a1 = A[d0 + 1][e], a2 = A[d0 + 2][e];
#pragma unroll
        for (int r = 0; r < 4; ++r) {
            float vv = vsf[rr0 + r][e];
            acc[r][0] += a0 * vv; acc[r][1] += a1 * vv; acc[r][2] += a2 * vv;
        }
    }
#pragma unroll
    for (int r = 0; r < 4; ++r)
#pragma unroll
        for (int j = 0; j < 3; ++j)
            z[(size_t)(r0 + rr0 + r) * 384 + h * 48 + d0 + j] = f2bf(acc[r][j]);
}

// ---------------------------------------------------------------- conv weight: f32 [O,C,3,3] -> bf16 [O, (dy*3+dx)*384 + c]
__global__ void reorder_w_kernel(const float* __restrict__ w, u16* __restrict__ wr, int n) {
    int i = blockIdx.x * blockDim.x + threadIdx.x;
    if (i < n) {
        int o = i / 3456, rem = i - o * 3456;
        int j = rem / 384, c = rem - j * 384;
        wr[i] = f2bf(w[(size_t)(o * 384 + c) * 9 + j]);
    }
}

// ---------------------------------------------------------------- (H, W) tail
__global__ void tail_kernel(const int* __restrict__ Hp, const int* __restrict__ Wp,
                            float* __restrict__ out, size_t base, int n_extra) {
    if (threadIdx.x == 0) {
        if (n_extra >= 1) out[base]     = (float)Hp[0];
        if (n_extra >= 2) out[base + 1] = (float)Wp[0];
    }
}

extern "C" void kernel_launch(void* const* d_in, const int* in_sizes, int n_in,
                              void* d_out, int out_size, void* d_ws, size_t ws_size,
                              hipStream_t stream) {
    const float* x      = (const float*)d_in[0];
    const float* ln1_g  = (const float*)d_in[1];
    const float* ln1_b  = (const float*)d_in[2];
    const float* w_qkv  = (const float*)d_in[3];
    const float* temp   = (const float*)d_in[4];
    const float* w_proj = (const float*)d_in[5];
    const float* gamma1 = (const float*)d_in[6];
    const float* ln2_g  = (const float*)d_in[7];
    const float* ln2_b  = (const float*)d_in[8];
    const float* mlp_w1 = (const float*)d_in[9];
    const float* bn1_g  = (const float*)d_in[10];
    const float* bn1_b  = (const float*)d_in[11];
    const float* bn1_m  = (const float*)d_in[12];
    const float* bn1_v  = (const float*)d_in[13];
    const float* mlp_w2 = (const float*)d_in[14];
    const float* bn2_g  = (const float*)d_in[15];
    const float* bn2_b  = (const float*)d_in[16];
    const float* bn2_m  = (const float*)d_in[17];
    const float* bn2_v  = (const float*)d_in[18];
    const float* gamma2 = (const float*)d_in[19];
    const float* ln3_g  = (const float*)d_in[20];
    const float* ln3_b  = (const float*)d_in[21];
    const float* pconv1 = (const float*)d_in[22];
    const float* pbn_g  = (const float*)d_in[23];
    const float* pbn_b  = (const float*)d_in[24];
    const float* pbn_m  = (const float*)d_in[25];
    const float* pbn_v  = (const float*)d_in[26];
    const float* pconv2 = (const float*)d_in[27];
    const float* gamma3 = (const float*)d_in[28];
    const int* Hp = (const int*)d_in[29];
    const int* Wp = (const int*)d_in[30];

    const int M = 36864, C = 384, C2 = 768, NQKV = 1152, KC = 3456;
    const size_t NBNC = (size_t)M * C;                 // 14,155,776

    const size_t SZ_XF  = NBNC * 4;                    //  56,623,104  f32 residual stream
    const size_t SZ_LN  = NBNC * 2;                    //  28,311,552  bf16 LN out / attn z
    const size_t SZ_BIG = (size_t)M * NQKV * 2;        //  84,934,656  bf16 qkv / mlp hidden / zero page
    const size_t SZ_P3  = SZ_LN;                       //  28,311,552  attnb + bf16 weights, later conv1 out
    const size_t SZ_W   = (size_t)C * KC * 2;          //   2,654,208  per reordered conv weight
    if (ws_size < SZ_XF + SZ_LN + SZ_BIG + SZ_P3 + 2 * SZ_W) return;

    char* ws = (char*)d_ws;
    float* xf     = (float*)ws;
    u16*   lnbuf  = (u16*)(ws + SZ_XF);
    u16*   big    = (u16*)(ws + SZ_XF + SZ_LN);
    char*  p3     = ws + SZ_XF + SZ_LN + SZ_BIG;
    float* attnb  = (float*)p3;                                      // 1,179,648 B
    u16*   wqkvb  = (u16*)(p3 + 1179648);
    u16*   wprojb = (u16*)(p3 + 1179648 + 884736);
    u16*   w1b    = (u16*)(p3 + 1179648 + 884736 + 294912);
    u16*   w2b    = (u16*)(p3 + 1179648 + 884736 + 294912 + 589824);
    u16*   convbf = (u16*)p3;                                        // conv1 output (bf16, M*C)
    u16*   w1r    = (u16*)(p3 + SZ_P3);
    u16*   w2r    = (u16*)(p3 + SZ_P3 + SZ_W);
    u16*   zp     = big;                                             // 4 KB zero page (big is dead in block 3)

    const int n4 = (int)(NBNC / 4);
    const int n_extra = out_size - (int)NBNC;

    copyf_kernel<<<(n4 + 255) / 256, 256, 0, stream>>>(x, xf, n4);

    // weight conversions (f32 -> bf16)
    cvt_f2b_kernel<<<(NQKV * C / 4 + 255) / 256, 256, 0, stream>>>(w_qkv, wqkvb, NQKV * C / 4);
    cvt_f2b_kernel<<<(C * C / 4 + 255) / 256, 256, 0, stream>>>(w_proj, wprojb, C * C / 4);
    cvt_f2b_kernel<<<(C2 * C / 4 + 255) / 256, 256, 0, stream>>>(mlp_w1, w1b, C2 * C / 4);
    cvt_f2b_kernel<<<(C * C2 / 4 + 255) / 256, 256, 0, stream>>>(mlp_w2, w2b, C * C2 / 4);

    // --- attention block ---
    ln_kernel<<<M, 64, 0, stream>>>(xf, ln1_g, ln1_b, lnbuf);
    gemm_nt<0, 0><<<dim3(NQKV / 128, M / 128), 256, 0, stream>>>(
        lnbuf, wqkvb, M, NQKV, C, big, NQKV, nullptr, nullptr, nullptr, nullptr, nullptr, nullptr, nullptr, nullptr);
    attn_kernel<<<128, 256, 0, stream>>>(big, temp, attnb);
    attnout_kernel<<<dim3(M / 64, 8), 256, 0, stream>>>(big, attnb, lnbuf);
    gemm_nt<0, 3><<<dim3(C / 128, M / 128), 256, 0, stream>>>(
        lnbuf, wprojb, M, C, C, nullptr, 0, xf, nullptr, nullptr, nullptr, nullptr, nullptr, gamma1, nullptr);

    // --- ConvMlp block (1x1 convs + eval BN) ---
    ln_kernel<<<M, 64, 0, stream>>>(xf, ln2_g, ln2_b, lnbuf);
    gemm_nt<0, 1><<<dim3(C2 / 128, M / 128), 256, 0, stream>>>(
        lnbuf, w1b, M, C2, C, big, C2, nullptr, nullptr, bn1_g, bn1_b, bn1_m, bn1_v, nullptr, nullptr);
    gemm_nt<0, 2><<<dim3(C / 128, M / 128), 256, 0, stream>>>(
        big, w2b, M, C, C2, nullptr, 0, xf, nullptr, bn2_g, bn2_b, bn2_m, bn2_v, gamma2, nullptr);

    // --- projection block (3x3 conv -> BN -> GELU -> 3x3 conv), implicit im2col GEMMs ---
    ln_kernel<<<M, 64, 0, stream>>>(xf, ln3_g, ln3_b, lnbuf);
    reorder_w_kernel<<<(C * KC + 255) / 256, 256, 0, stream>>>(pconv1, w1r, C * KC);
    reorder_w_kernel<<<(C * KC + 255) / 256, 256, 0, stream>>>(pconv2, w2r, C * KC);
    zero_kernel<<<8, 256, 0, stream>>>(zp, 2048);      // 4 KB zero page for im2col halo
    gemm_nt<1, 1><<<dim3(C / 128, M / 128), 256, 0, stream>>>(
        lnbuf, w1r, M, C, KC, convbf, C, nullptr, nullptr, pbn_g, pbn_b, pbn_m, pbn_v, nullptr, zp);
    gemm_nt<1, 4><<<dim3(C / 128, M / 128), 256, 0, stream>>>(
        convbf, w2r, M, C, KC, nullptr, 0, xf, (float*)d_out, nullptr, nullptr, nullptr, nullptr, gamma3, zp);

    tail_kernel<<<1, 64, 0, stream>>>(Hp, Wp, (float*)d_out, NBNC, n_extra);
}

// Round 4
// 953.159 us; speedup vs baseline: 1.2527x; 1.0754x over previous
//
#include <hip/hip_runtime.h>
#include <hip/hip_bf16.h>

typedef unsigned short u16;
typedef __attribute__((ext_vector_type(8))) short short8;   // 8 bf16 (4 VGPRs) — MFMA A/B frag
typedef __attribute__((ext_vector_type(4))) float floatx4;  // MFMA C/D frag

#define LN_EPS 1e-5f

__device__ __forceinline__ float bf2f(u16 u) {
    unsigned int i = ((unsigned int)u) << 16;
    float f; __builtin_memcpy(&f, &i, 4); return f;
}
__device__ __forceinline__ u16 f2bf(float f) {
    __hip_bfloat16 h = __float2bfloat16(f);   // RNE
    u16 u; __builtin_memcpy(&u, &h, 2); return u;
}

// async global->LDS, 16 B per lane; lds dest must be wave-uniform (HW adds lane*16)
__device__ __forceinline__ void gl_lds16(const u16* g, u16* l) {
    __builtin_amdgcn_global_load_lds(
        (const __attribute__((address_space(1))) void*)(const void*)g,
        (__attribute__((address_space(3))) void*)(void*)l,
        16, 0, 0);
}

// 16 MFMA on one 32-wide k-half (A half-tile, B half-tile in [128][32] layout)
__device__ __forceinline__ void mfma_half(const u16* __restrict__ Ah, const u16* __restrict__ Bh,
                                          int wm, int wn, int fr, int kq, floatx4 (*acc)[4]) {
    short8 af[4], bfr[4];
#pragma unroll
    for (int i = 0; i < 4; ++i) af[i]  = *(const short8*)(&Ah[(wm + i * 16 + fr) * 32 + kq]);
#pragma unroll
    for (int j = 0; j < 4; ++j) bfr[j] = *(const short8*)(&Bh[(wn + j * 16 + fr) * 32 + kq]);
#pragma unroll
    for (int i = 0; i < 4; ++i)
#pragma unroll
        for (int j = 0; j < 4; ++j)
            acc[i][j] = __builtin_amdgcn_mfma_f32_16x16x32_bf16(af[i], bfr[j], acc[i][j], 0, 0, 0);
}

// ---------------------------------------------------------------- f32 -> bf16 (weights)
__global__ void cvt_f2b_kernel(const float* __restrict__ in, u16* __restrict__ out, int n4) {
    int i = blockIdx.x * blockDim.x + threadIdx.x;
    if (i < n4) {
        float4 f = ((const float4*)in)[i];
        ((ushort4*)out)[i] = make_ushort4(f2bf(f.x), f2bf(f.y), f2bf(f.z), f2bf(f.w));
    }
}

__global__ void zero_kernel(u16* __restrict__ p, int n) {
    int i = blockIdx.x * blockDim.x + threadIdx.x;
    if (i < n) p[i] = 0;
}

// ---------------------------------------------------------------- LayerNorm over C=384, one wave per row
__global__ __launch_bounds__(64)
void ln_kernel(const float* __restrict__ xf, const float* __restrict__ g,
               const float* __restrict__ b, u16* __restrict__ out) {
    const int row = blockIdx.x;
    const int lane = threadIdx.x;
    const float* xr = xf + (size_t)row * 384;
    float v[6], s = 0.f, s2 = 0.f;
#pragma unroll
    for (int i = 0; i < 6; ++i) { v[i] = xr[lane + i * 64]; s += v[i]; s2 += v[i] * v[i]; }
#pragma unroll
    for (int off = 32; off; off >>= 1) { s += __shfl_xor(s, off); s2 += __shfl_xor(s2, off); }
    float mean = s * (1.0f / 384.0f);
    float var  = s2 * (1.0f / 384.0f) - mean * mean;
    float rstd = rsqrtf(var + LN_EPS);
    u16* orow = out + (size_t)row * 384;
#pragma unroll
    for (int i = 0; i < 6; ++i) {
        int c = lane + i * 64;
        orow[c] = f2bf((v[i] - mean) * rstd * g[c] + b[c]);
    }
}

// ---------------------------------------------------------------- MFMA NT GEMM: C[M,N] = A[M,K] * B[N,K]^T   (A,B bf16)
// BK=64 as two physical [128][32] half-tiles (identical bank pattern & staging map as BK=32).
// ACONV: 0 = A plain [M,K]; 1 = implicit im2col of [B*2304, 384], H=W=48, K=3456, k=(dy*3+dx)*384+c
// EPI:   0 = store bf16; 1 = BN+GELU -> bf16; 2 = BN -> xf += gamma*val; 3 = xf += gamma*val;
//        4 = ofb = xf + gamma*val (f32, fused finalize); 5 = xf = xin + gamma*val
template<int ACONV, int EPI>
__global__ __launch_bounds__(256)
void gemm_nt(const u16* __restrict__ A, const u16* __restrict__ Bm,
             int M, int N, int K,
             u16* __restrict__ Obf, int ldo,
             float* __restrict__ xf, float* __restrict__ ofb, const float* __restrict__ xin,
             const float* __restrict__ bn_g, const float* __restrict__ bn_b,
             const float* __restrict__ bn_m, const float* __restrict__ bn_v,
             const float* __restrict__ gamma, const u16* __restrict__ zp) {
    __shared__ u16 As[2][128 * 32];
    __shared__ u16 Bs[2][128 * 32];

    const int tid  = threadIdx.x;
    const int m0   = blockIdx.y * 128;
    const int n0   = blockIdx.x * 128;
    const int lane = tid & 63;
    const int wave = tid >> 6;
    const int wm   = (wave >> 1) * 64;
    const int wn   = (wave & 1) * 64;
    const int fr   = lane & 15;
    const int kq   = (lane >> 4) * 8;

    // staging geometry (per half-tile): it=0 -> rows tid>>2, it=1 -> rows (tid>>2)+64; kc=(tid&3)*8
    const int row0 = tid >> 2;
    const int kc0  = (tid & 3) * 8;
    u16* lA0 = &As[0][wave * 512];          u16* lA1 = &As[0][2048 + wave * 512];
    u16* lA0h = &As[1][wave * 512];         u16* lA1h = &As[1][2048 + wave * 512];
    u16* lB0 = &Bs[0][wave * 512];          u16* lB1 = &Bs[0][2048 + wave * 512];
    u16* lB0h = &Bs[1][wave * 512];         u16* lB1h = &Bs[1][2048 + wave * 512];

    floatx4 acc[4][4];
#pragma unroll
    for (int i = 0; i < 4; ++i)
#pragma unroll
        for (int j = 0; j < 4; ++j) acc[i][j] = (floatx4){0.f, 0.f, 0.f, 0.f};

    if (ACONV == 0) {
        const u16* a0 = A + (size_t)(m0 + row0) * K + kc0;
        const u16* a1 = A + (size_t)(m0 + row0 + 64) * K + kc0;
        const u16* b0 = Bm + (size_t)(n0 + row0) * K + kc0;
        const u16* b1 = Bm + (size_t)(n0 + row0 + 64) * K + kc0;
        for (int k0 = 0; k0 < K; k0 += 64) {
            gl_lds16(a0, lA0); gl_lds16(a1, lA1); gl_lds16(a0 + 32, lA0h); gl_lds16(a1 + 32, lA1h);
            gl_lds16(b0, lB0); gl_lds16(b1, lB1); gl_lds16(b0 + 32, lB0h); gl_lds16(b1 + 32, lB1h);
            a0 += 64; a1 += 64; b0 += 64; b1 += 64;
            __syncthreads();
            mfma_half(As[0], Bs[0], wm, wn, fr, kq, acc);
            mfma_half(As[1], Bs[1], wm, wn, fr, kq, acc);
            __syncthreads();
        }
    } else {
        const int bimg = m0 / 2304;
        const int nb   = m0 - bimg * 2304;
        const int nA   = nb + row0;
        const int y0 = nA / 48,        x0 = nA - y0 * 48;
        const int y1 = (nA + 64) / 48, x1 = (nA + 64) - ((nA + 64) / 48) * 48;
        const u16* img = A + (size_t)bimg * 2304 * 384;
        const u16* b0 = Bm + (size_t)(n0 + row0) * K + kc0;
        const u16* b1 = Bm + (size_t)(n0 + row0 + 64) * K + kc0;
        for (int j = 0; j < 9; ++j) {
            const int dy = j / 3 - 1, dx = j % 3 - 1;
            const int yy0 = y0 + dy, xx0 = x0 + dx;
            const int yy1 = y1 + dy, xx1 = x1 + dx;
            const bool v0 = ((unsigned)yy0 < 48u) & ((unsigned)xx0 < 48u);
            const bool v1 = ((unsigned)yy1 < 48u) & ((unsigned)xx1 < 48u);
            const u16* a0 = v0 ? img + (size_t)(yy0 * 48 + xx0) * 384 + kc0 : zp;
            const u16* a1 = v1 ? img + (size_t)(yy1 * 48 + xx1) * 384 + kc0 : zp;
            for (int c0 = 0; c0 < 384; c0 += 64) {
                gl_lds16(a0, lA0); gl_lds16(a1, lA1); gl_lds16(a0 + 32, lA0h); gl_lds16(a1 + 32, lA1h);
                gl_lds16(b0, lB0); gl_lds16(b1, lB1); gl_lds16(b0 + 32, lB0h); gl_lds16(b1 + 32, lB1h);
                a0 += 64; a1 += 64; b0 += 64; b1 += 64;   // zp page 4 KB: max offset 24+320+32+8 u16, in-bounds
                __syncthreads();
                mfma_half(As[0], Bs[0], wm, wn, fr, kq, acc);
                mfma_half(As[1], Bs[1], wm, wn, fr, kq, acc);
                __syncthreads();
            }
        }
    }

    // Epilogue. C/D layout: col = lane&15, row = (lane>>4)*4 + reg   [verified m89/m91]
    const int quad4 = (lane >> 4) * 4;
#pragma unroll
    for (int j = 0; j < 4; ++j) {
        int col = n0 + wn + j * 16 + fr;
        float bscale = 0.f, bshift = 0.f, gam = 0.f;
        if (EPI == 1 || EPI == 2) {
            bscale = bn_g[col] * rsqrtf(bn_v[col] + LN_EPS);
            bshift = bn_b[col] - bn_m[col] * bscale;
        }
        if (EPI >= 2) gam = gamma[col];
#pragma unroll
        for (int i = 0; i < 4; ++i) {
#pragma unroll
            for (int r = 0; r < 4; ++r) {
                int row = m0 + wm + i * 16 + quad4 + r;
                float v = acc[i][j][r];
                if (EPI == 0) {
                    Obf[(size_t)row * ldo + col] = f2bf(v);
                } else if (EPI == 1) {
                    float t = v * bscale + bshift;
                    t = 0.5f * t * (1.0f + erff(t * 0.70710678118654752f));
                    Obf[(size_t)row * ldo + col] = f2bf(t);
                } else if (EPI == 2) {
                    float t = v * bscale + bshift;
                    xf[(size_t)row * N + col] += gam * t;
                } else if (EPI == 3) {
                    xf[(size_t)row * N + col] += gam * v;
                } else if (EPI == 4) {
                    ofb[(size_t)row * N + col] = xf[(size_t)row * N + col] + gam * v;
                } else {
                    xf[(size_t)row * N + col] = xin[(size_t)row * N + col] + gam * v;
                }
            }
        }
    }
}

// ---------------------------------------------------------------- channel attention: per (b,h) Gram + norms + softmax
__global__ __launch_bounds__(256)
void attn_kernel(const u16* __restrict__ qkv, const float* __restrict__ temp,
                 float* __restrict__ attnb) {
    const int bh = blockIdx.x;
    const int b = bh >> 3, h = bh & 7;
    const int tid = threadIdx.x;
    __shared__ float qsf[64][48];
    __shared__ float ksf[64][48];
    __shared__ float qns[48], kns[48];
    __shared__ float S[48][49];

    float acc9[3][3];
#pragma unroll
    for (int i = 0; i < 3; ++i)
#pragma unroll
        for (int j = 0; j < 3; ++j) acc9[i][j] = 0.f;
    float qn2 = 0.f, kn2 = 0.f;

    const int qoff = h * 48;
    const int koff = 384 + h * 48;
    const int d0 = (tid >> 4) * 3;
    const int e0 = (tid & 15) * 3;

    for (int n0 = 0; n0 < 2304; n0 += 64) {
#pragma unroll
        for (int it = 0; it < 6; ++it) {
            int chunk = tid + it * 256;          // 0..1535: [q 768 | k 768] chunks of 4 bf16
            int mat = chunk >= 768 ? 1 : 0;
            int rem = chunk - mat * 768;
            int nn = rem / 12, u = rem - nn * 12;
            ushort4 raw = *(const ushort4*)(qkv + (size_t)(b * 2304 + n0 + nn) * 1152 +
                                            (mat ? koff : qoff) + u * 4);
            float4 f = make_float4(bf2f(raw.x), bf2f(raw.y), bf2f(raw.z), bf2f(raw.w));
            if (mat) *(float4*)&ksf[nn][u * 4] = f;
            else     *(float4*)&qsf[nn][u * 4] = f;
        }
        __syncthreads();
#pragma unroll 4
        for (int nn = 0; nn < 64; ++nn) {
            float q0 = qsf[nn][d0], q1 = qsf[nn][d0 + 1], q2 = qsf[nn][d0 + 2];
            float k0v = ksf[nn][e0], k1v = ksf[nn][e0 + 1], k2v = ksf[nn][e0 + 2];
            acc9[0][0] += q0 * k0v; acc9[0][1] += q0 * k1v; acc9[0][2] += q0 * k2v;
            acc9[1][0] += q1 * k0v; acc9[1][1] += q1 * k1v; acc9[1][2] += q1 * k2v;
            acc9[2][0] += q2 * k0v; acc9[2][1] += q2 * k1v; acc9[2][2] += q2 * k2v;
        }
        if (tid < 48) {
            for (int nn = 0; nn < 64; ++nn) { float q = qsf[nn][tid]; qn2 += q * q; }
        } else if (tid >= 128 && tid < 176) {
            int e = tid - 128;
            for (int nn = 0; nn < 64; ++nn) { float k = ksf[nn][e]; kn2 += k * k; }
        }
        __syncthreads();
    }

    if (tid < 48) qns[tid] = fmaxf(sqrtf(qn2), 1e-12f);
    else if (tid >= 128 && tid < 176) kns[tid - 128] = fmaxf(sqrtf(kn2), 1e-12f);
    __syncthreads();

    float tf = temp[h];
#pragma unroll
    for (int i = 0; i < 3; ++i)
#pragma unroll
        for (int j = 0; j < 3; ++j)
            S[d0 + i][e0 + j] = acc9[i][j] * tf / (qns[d0 + i] * kns[e0 + j]);
    __syncthreads();

    if (tid < 48) {
        float mx = -1e30f;
        for (int e = 0; e < 48; ++e) mx = fmaxf(mx, S[tid][e]);
        float sum = 0.f;
        for (int e = 0; e < 48; ++e) { float t = __expf(S[tid][e] - mx); S[tid][e] = t; sum += t; }
        float inv = 1.0f / sum;
        float* dst = attnb + ((size_t)bh * 48 + tid) * 48;
        for (int e = 0; e < 48; ++e) dst[e] = S[tid][e] * inv;
    }
}

// ---------------------------------------------------------------- out[b,n,h*48+d] = sum_e attn[b,h,d,e] * v[b,n,h*48+e]
__global__ __launch_bounds__(256)
void attnout_kernel(const u16* __restrict__ qkv, const float* __restrict__ attnb,
                    u16* __restrict__ z) {
    const int r0 = blockIdx.x * 64;
    const int h  = blockIdx.y;
    const int b  = r0 / 2304;
    const int tid = threadIdx.x;
    __shared__ float A[48][49];
    __shared__ float vsf[64][48];

    const float* asrc = attnb + (size_t)(b * 8 + h) * 2304;
    for (int i = tid; i < 2304; i += 256) {
        int d = i / 48, e = i - d * 48;
        A[d][e] = asrc[i];
    }
    const int voff = 768 + h * 48;
    for (int i = tid; i < 768; i += 256) {
        int nn = i / 12, u = i - nn * 12;
        ushort4 raw = *(const ushort4*)(qkv + (size_t)(r0 + nn) * 1152 + voff + u * 4);
        float4 f = make_float4(bf2f(raw.x), bf2f(raw.y), bf2f(raw.z), bf2f(raw.w));
        *(float4*)&vsf[nn][u * 4] = f;
    }
    __syncthreads();

    const int rr0 = (tid >> 4) * 4;
    const int d0  = (tid & 15) * 3;
    float acc[4][3];
#pragma unroll
    for (int r = 0; r < 4; ++r)
#pragma unroll
        for (int j = 0; j < 3; ++j) acc[r][j] = 0.f;

#pragma unroll 4
    for (int e = 0; e < 48; ++e) {
        float a0 = A[d0][e], a1 = A[d0 + 1][e], a2 = A[d0 + 2][e];
#pragma unroll
        for (int r = 0; r < 4; ++r) {
            float vv = vsf[rr0 + r][e];
            acc[r][0] += a0 * vv; acc[r][1] += a1 * vv; acc[r][2] += a2 * vv;
        }
    }
#pragma unroll
    for (int r = 0; r < 4; ++r)
#pragma unroll
        for (int j = 0; j < 3; ++j)
            z[(size_t)(r0 + rr0 + r) * 384 + h * 48 + d0 + j] = f2bf(acc[r][j]);
}

// ---------------------------------------------------------------- conv weight: f32 [O,C,3,3] -> bf16 [O, (dy*3+dx)*384 + c]
__global__ void reorder_w_kernel(const float* __restrict__ w, u16* __restrict__ wr, int n) {
    int i = blockIdx.x * blockDim.x + threadIdx.x;
    if (i < n) {
        int o = i / 3456, rem = i - o * 3456;
        int j = rem / 384, c = rem - j * 384;
        wr[i] = f2bf(w[(size_t)(o * 384 + c) * 9 + j]);
    }
}

// ---------------------------------------------------------------- (H, W) tail
__global__ void tail_kernel(const int* __restrict__ Hp, const int* __restrict__ Wp,
                            float* __restrict__ out, size_t base, int n_extra) {
    if (threadIdx.x == 0) {
        if (n_extra >= 1) out[base]     = (float)Hp[0];
        if (n_extra >= 2) out[base + 1] = (float)Wp[0];
    }
}

extern "C" void kernel_launch(void* const* d_in, const int* in_sizes, int n_in,
                              void* d_out, int out_size, void* d_ws, size_t ws_size,
                              hipStream_t stream) {
    const float* x      = (const float*)d_in[0];
    const float* ln1_g  = (const float*)d_in[1];
    const float* ln1_b  = (const float*)d_in[2];
    const float* w_qkv  = (const float*)d_in[3];
    const float* temp   = (const float*)d_in[4];
    const float* w_proj = (const float*)d_in[5];
    const float* gamma1 = (const float*)d_in[6];
    const float* ln2_g  = (const float*)d_in[7];
    const float* ln2_b  = (const float*)d_in[8];
    const float* mlp_w1 = (const float*)d_in[9];
    const float* bn1_g  = (const float*)d_in[10];
    const float* bn1_b  = (const float*)d_in[11];
    const float* bn1_m  = (const float*)d_in[12];
    const float* bn1_v  = (const float*)d_in[13];
    const float* mlp_w2 = (const float*)d_in[14];
    const float* bn2_g  = (const float*)d_in[15];
    const float* bn2_b  = (const float*)d_in[16];
    const float* bn2_m  = (const float*)d_in[17];
    const float* bn2_v  = (const float*)d_in[18];
    const float* gamma2 = (const float*)d_in[19];
    const float* ln3_g  = (const float*)d_in[20];
    const float* ln3_b  = (const float*)d_in[21];
    const float* pconv1 = (const float*)d_in[22];
    const float* pbn_g  = (const float*)d_in[23];
    const float* pbn_b  = (const float*)d_in[24];
    const float* pbn_m  = (const float*)d_in[25];
    const float* pbn_v  = (const float*)d_in[26];
    const float* pconv2 = (const float*)d_in[27];
    const float* gamma3 = (const float*)d_in[28];
    const int* Hp = (const int*)d_in[29];
    const int* Wp = (const int*)d_in[30];

    const int M = 36864, C = 384, C2 = 768, NQKV = 1152, KC = 3456;
    const size_t NBNC = (size_t)M * C;                 // 14,155,776

    const size_t SZ_XF  = NBNC * 4;                    //  f32 residual stream
    const size_t SZ_LN  = NBNC * 2;                    //  bf16 LN out / attn z
    const size_t SZ_BIG = (size_t)M * NQKV * 2;        //  bf16 qkv / mlp hidden / zero page
    const size_t SZ_P3  = SZ_LN;                       //  attnb + bf16 weights, later conv1 out
    const size_t SZ_W   = (size_t)C * KC * 2;
    if (ws_size < SZ_XF + SZ_LN + SZ_BIG + SZ_P3 + 2 * SZ_W) return;

    char* ws = (char*)d_ws;
    float* xf     = (float*)ws;
    u16*   lnbuf  = (u16*)(ws + SZ_XF);
    u16*   big    = (u16*)(ws + SZ_XF + SZ_LN);
    char*  p3     = ws + SZ_XF + SZ_LN + SZ_BIG;
    float* attnb  = (float*)p3;                                      // 1,179,648 B
    u16*   wqkvb  = (u16*)(p3 + 1179648);
    u16*   wprojb = (u16*)(p3 + 1179648 + 884736);
    u16*   w1b    = (u16*)(p3 + 1179648 + 884736 + 294912);
    u16*   w2b    = (u16*)(p3 + 1179648 + 884736 + 294912 + 589824);
    u16*   convbf = (u16*)p3;                                        // conv1 output (bf16, M*C)
    u16*   w1r    = (u16*)(p3 + SZ_P3);
    u16*   w2r    = (u16*)(p3 + SZ_P3 + SZ_W);
    u16*   zp     = big;                                             // 4 KB zero page (big is dead in block 3)

    const int n_extra = out_size - (int)NBNC;

    // weight conversions (f32 -> bf16)
    cvt_f2b_kernel<<<(NQKV * C / 4 + 255) / 256, 256, 0, stream>>>(w_qkv, wqkvb, NQKV * C / 4);
    cvt_f2b_kernel<<<(C * C / 4 + 255) / 256, 256, 0, stream>>>(w_proj, wprojb, C * C / 4);
    cvt_f2b_kernel<<<(C2 * C / 4 + 255) / 256, 256, 0, stream>>>(mlp_w1, w1b, C2 * C / 4);
    cvt_f2b_kernel<<<(C * C2 / 4 + 255) / 256, 256, 0, stream>>>(mlp_w2, w2b, C * C2 / 4);

    // --- attention block ---  (ln1 reads input x directly; no residual copy)
    ln_kernel<<<M, 64, 0, stream>>>(x, ln1_g, ln1_b, lnbuf);
    gemm_nt<0, 0><<<dim3(NQKV / 128, M / 128), 256, 0, stream>>>(
        lnbuf, wqkvb, M, NQKV, C, big, NQKV, nullptr, nullptr, nullptr,
        nullptr, nullptr, nullptr, nullptr, nullptr, nullptr);
    attn_kernel<<<128, 256, 0, stream>>>(big, temp, attnb);
    attnout_kernel<<<dim3(M / 64, 8), 256, 0, stream>>>(big, attnb, lnbuf);
    gemm_nt<0, 5><<<dim3(C / 128, M / 128), 256, 0, stream>>>(        // xf = x + gamma1 * proj
        lnbuf, wprojb, M, C, C, nullptr, 0, xf, nullptr, x,
        nullptr, nullptr, nullptr, nullptr, gamma1, nullptr);

    // --- ConvMlp block (1x1 convs + eval BN) ---
    ln_kernel<<<M, 64, 0, stream>>>(xf, ln2_g, ln2_b, lnbuf);
    gemm_nt<0, 1><<<dim3(C2 / 128, M / 128), 256, 0, stream>>>(
        lnbuf, w1b, M, C2, C, big, C2, nullptr, nullptr, nullptr,
        bn1_g, bn1_b, bn1_m, bn1_v, nullptr, nullptr);
    gemm_nt<0, 2><<<dim3(C / 128, M / 128), 256, 0, stream>>>(
        big, w2b, M, C, C2, nullptr, 0, xf, nullptr, nullptr,
        bn2_g, bn2_b, bn2_m, bn2_v, gamma2, nullptr);

    // --- projection block (3x3 conv -> BN -> GELU -> 3x3 conv), implicit im2col GEMMs ---
    ln_kernel<<<M, 64, 0, stream>>>(xf, ln3_g, ln3_b, lnbuf);
    reorder_w_kernel<<<(C * KC + 255) / 256, 256, 0, stream>>>(pconv1, w1r, C * KC);
    reorder_w_kernel<<<(C * KC + 255) / 256, 256, 0, stream>>>(pconv2, w2r, C * KC);
    zero_kernel<<<8, 256, 0, stream>>>(zp, 2048);      // 4 KB zero page for im2col halo
    gemm_nt<1, 1><<<dim3(C / 128, M / 128), 256, 0, stream>>>(
        lnbuf, w1r, M, C, KC, convbf, C, nullptr, nullptr, nullptr,
        pbn_g, pbn_b, pbn_m, pbn_v, nullptr, zp);
    gemm_nt<1, 4><<<dim3(C / 128, M / 128), 256, 0, stream>>>(
        convbf, w2r, M, C, KC, nullptr, 0, xf, (float*)d_out, nullptr,
        nullptr, nullptr, nullptr, nullptr, gamma3, zp);

    tail_kernel<<<1, 64, 0, stream>>>(Hp, Wp, (float*)d_out, NBNC, n_extra);
}

// Round 5
// 881.478 us; speedup vs baseline: 1.3546x; 1.0813x over previous
//
#include <hip/hip_runtime.h>
#include <hip/hip_bf16.h>

typedef unsigned short u16;
typedef __attribute__((ext_vector_type(8))) short short8;   // 8 bf16 (4 VGPRs) — MFMA A/B frag
typedef __attribute__((ext_vector_type(4))) float floatx4;  // MFMA C/D frag

#define LN_EPS 1e-5f

__device__ __forceinline__ float bf2f(u16 u) {
    unsigned int i = ((unsigned int)u) << 16;
    float f; __builtin_memcpy(&f, &i, 4); return f;
}
__device__ __forceinline__ u16 f2bf(float f) {
    __hip_bfloat16 h = __float2bfloat16(f);   // RNE
    u16 u; __builtin_memcpy(&u, &h, 2); return u;
}

// async global->LDS, 16 B per lane; lds dest must be wave-uniform (HW adds lane*16)
__device__ __forceinline__ void gl_lds16(const u16* g, u16* l) {
    __builtin_amdgcn_global_load_lds(
        (const __attribute__((address_space(1))) void*)(const void*)g,
        (__attribute__((address_space(3))) void*)(void*)l,
        16, 0, 0);
}

// 16 MFMA on one 32-wide k-half (A half-tile, B half-tile in [128][32] layout)
__device__ __forceinline__ void mfma_half(const u16* __restrict__ Ah, const u16* __restrict__ Bh,
                                          int wm, int wn, int fr, int kq, floatx4 (*acc)[4]) {
    short8 af[4], bfr[4];
#pragma unroll
    for (int i = 0; i < 4; ++i) af[i]  = *(const short8*)(&Ah[(wm + i * 16 + fr) * 32 + kq]);
#pragma unroll
    for (int j = 0; j < 4; ++j) bfr[j] = *(const short8*)(&Bh[(wn + j * 16 + fr) * 32 + kq]);
#pragma unroll
    for (int i = 0; i < 4; ++i)
#pragma unroll
        for (int j = 0; j < 4; ++j)
            acc[i][j] = __builtin_amdgcn_mfma_f32_16x16x32_bf16(af[i], bfr[j], acc[i][j], 0, 0, 0);
}

// ---------------------------------------------------------------- f32 -> bf16 (weights)
__global__ void cvt_f2b_kernel(const float* __restrict__ in, u16* __restrict__ out, int n4) {
    int i = blockIdx.x * blockDim.x + threadIdx.x;
    if (i < n4) {
        float4 f = ((const float4*)in)[i];
        ((ushort4*)out)[i] = make_ushort4(f2bf(f.x), f2bf(f.y), f2bf(f.z), f2bf(f.w));
    }
}

__global__ void zero_kernel(u16* __restrict__ p, int n) {
    int i = blockIdx.x * blockDim.x + threadIdx.x;
    if (i < n) p[i] = 0;
}

// ---------------------------------------------------------------- LayerNorm over C=384, one wave per row
__global__ __launch_bounds__(64)
void ln_kernel(const float* __restrict__ xf, const float* __restrict__ g,
               const float* __restrict__ b, u16* __restrict__ out) {
    const int row = blockIdx.x;
    const int lane = threadIdx.x;
    const float* xr = xf + (size_t)row * 384;
    float v[6], s = 0.f, s2 = 0.f;
#pragma unroll
    for (int i = 0; i < 6; ++i) { v[i] = xr[lane + i * 64]; s += v[i]; s2 += v[i] * v[i]; }
#pragma unroll
    for (int off = 32; off; off >>= 1) { s += __shfl_xor(s, off); s2 += __shfl_xor(s2, off); }
    float mean = s * (1.0f / 384.0f);
    float var  = s2 * (1.0f / 384.0f) - mean * mean;
    float rstd = rsqrtf(var + LN_EPS);
    u16* orow = out + (size_t)row * 384;
#pragma unroll
    for (int i = 0; i < 6; ++i) {
        int c = lane + i * 64;
        orow[c] = f2bf((v[i] - mean) * rstd * g[c] + b[c]);
    }
}

// ---------------------------------------------------------------- MFMA NT GEMM: C[M,N] = A[M,K] * B[N,K]^T   (A,B bf16)
// BK=64 as two physical [128][32] half-tiles. XCD-aware swizzle: g%8 assumed = XCD; each XCD gets a
// contiguous m-band so the 9-tap im2col re-reads / n-tile A re-reads hit its 4 MB L2.
// ACONV: 0 = A plain [M,K]; 1 = implicit im2col of [B*2304, 384], H=W=48, K=3456, k=(dy*3+dx)*384+c
// EPI:   0 = store bf16; 1 = BN+GELU -> bf16; 2 = BN -> xf += gamma*val; 3 = xf += gamma*val;
//        4 = ofb = xf + gamma*val (f32, fused finalize); 5 = xf = xin + gamma*val
template<int ACONV, int EPI>
__global__ __launch_bounds__(256)
void gemm_nt(const u16* __restrict__ A, const u16* __restrict__ Bm,
             int M, int N, int K,
             u16* __restrict__ Obf, int ldo,
             float* __restrict__ xf, float* __restrict__ ofb, const float* __restrict__ xin,
             const float* __restrict__ bn_g, const float* __restrict__ bn_b,
             const float* __restrict__ bn_m, const float* __restrict__ bn_v,
             const float* __restrict__ gamma, const u16* __restrict__ zp) {
    __shared__ u16 As[2][128 * 32];
    __shared__ u16 Bs[2][128 * 32];

    const int tid  = threadIdx.x;
    // XCD swizzle: L = (g%8)*(G/8) + g/8 ; n_tile = L % gx (fast), m_tile = L / gx (contiguous band/XCD)
    const int gx = gridDim.x;
    const int g  = blockIdx.y * gx + blockIdx.x;
    const int G  = gx * gridDim.y;
    int L = g;
    if ((G & 7) == 0) L = (g & 7) * (G >> 3) + (g >> 3);
    const int n0 = (L % gx) * 128;
    const int m0 = (L / gx) * 128;

    const int lane = tid & 63;
    const int wave = tid >> 6;
    const int wm   = (wave >> 1) * 64;
    const int wn   = (wave & 1) * 64;
    const int fr   = lane & 15;
    const int kq   = (lane >> 4) * 8;

    // staging geometry (per half-tile): it=0 -> rows tid>>2, it=1 -> rows (tid>>2)+64; kc=(tid&3)*8
    const int row0 = tid >> 2;
    const int kc0  = (tid & 3) * 8;
    u16* lA0 = &As[0][wave * 512];          u16* lA1 = &As[0][2048 + wave * 512];
    u16* lA0h = &As[1][wave * 512];         u16* lA1h = &As[1][2048 + wave * 512];
    u16* lB0 = &Bs[0][wave * 512];          u16* lB1 = &Bs[0][2048 + wave * 512];
    u16* lB0h = &Bs[1][wave * 512];         u16* lB1h = &Bs[1][2048 + wave * 512];

    floatx4 acc[4][4];
#pragma unroll
    for (int i = 0; i < 4; ++i)
#pragma unroll
        for (int j = 0; j < 4; ++j) acc[i][j] = (floatx4){0.f, 0.f, 0.f, 0.f};

    if (ACONV == 0) {
        const u16* a0 = A + (size_t)(m0 + row0) * K + kc0;
        const u16* a1 = A + (size_t)(m0 + row0 + 64) * K + kc0;
        const u16* b0 = Bm + (size_t)(n0 + row0) * K + kc0;
        const u16* b1 = Bm + (size_t)(n0 + row0 + 64) * K + kc0;
        for (int k0 = 0; k0 < K; k0 += 64) {
            gl_lds16(a0, lA0); gl_lds16(a1, lA1); gl_lds16(a0 + 32, lA0h); gl_lds16(a1 + 32, lA1h);
            gl_lds16(b0, lB0); gl_lds16(b1, lB1); gl_lds16(b0 + 32, lB0h); gl_lds16(b1 + 32, lB1h);
            a0 += 64; a1 += 64; b0 += 64; b1 += 64;
            __syncthreads();
            mfma_half(As[0], Bs[0], wm, wn, fr, kq, acc);
            mfma_half(As[1], Bs[1], wm, wn, fr, kq, acc);
            __syncthreads();
        }
    } else {
        const int bimg = m0 / 2304;
        const int nb   = m0 - bimg * 2304;
        const int nA   = nb + row0;
        const int y0 = nA / 48,        x0 = nA - y0 * 48;
        const int y1 = (nA + 64) / 48, x1 = (nA + 64) - ((nA + 64) / 48) * 48;
        const u16* img = A + (size_t)bimg * 2304 * 384;
        const u16* b0 = Bm + (size_t)(n0 + row0) * K + kc0;
        const u16* b1 = Bm + (size_t)(n0 + row0 + 64) * K + kc0;
        for (int j = 0; j < 9; ++j) {
            const int dy = j / 3 - 1, dx = j % 3 - 1;
            const int yy0 = y0 + dy, xx0 = x0 + dx;
            const int yy1 = y1 + dy, xx1 = x1 + dx;
            const bool v0 = ((unsigned)yy0 < 48u) & ((unsigned)xx0 < 48u);
            const bool v1 = ((unsigned)yy1 < 48u) & ((unsigned)xx1 < 48u);
            const u16* a0 = v0 ? img + (size_t)(yy0 * 48 + xx0) * 384 + kc0 : zp;
            const u16* a1 = v1 ? img + (size_t)(yy1 * 48 + xx1) * 384 + kc0 : zp;
            for (int c0 = 0; c0 < 384; c0 += 64) {
                gl_lds16(a0, lA0); gl_lds16(a1, lA1); gl_lds16(a0 + 32, lA0h); gl_lds16(a1 + 32, lA1h);
                gl_lds16(b0, lB0); gl_lds16(b1, lB1); gl_lds16(b0 + 32, lB0h); gl_lds16(b1 + 32, lB1h);
                a0 += 64; a1 += 64; b0 += 64; b1 += 64;   // zp page 4 KB: max offset stays in-bounds
                __syncthreads();
                mfma_half(As[0], Bs[0], wm, wn, fr, kq, acc);
                mfma_half(As[1], Bs[1], wm, wn, fr, kq, acc);
                __syncthreads();
            }
        }
    }

    // Epilogue. C/D layout: col = lane&15, row = (lane>>4)*4 + reg   [verified m89/m91]
    const int quad4 = (lane >> 4) * 4;
#pragma unroll
    for (int j = 0; j < 4; ++j) {
        int col = n0 + wn + j * 16 + fr;
        float bscale = 0.f, bshift = 0.f, gam = 0.f;
        if (EPI == 1 || EPI == 2) {
            bscale = bn_g[col] * rsqrtf(bn_v[col] + LN_EPS);
            bshift = bn_b[col] - bn_m[col] * bscale;
        }
        if (EPI >= 2) gam = gamma[col];
#pragma unroll
        for (int i = 0; i < 4; ++i) {
#pragma unroll
            for (int r = 0; r < 4; ++r) {
                int row = m0 + wm + i * 16 + quad4 + r;
                float v = acc[i][j][r];
                if (EPI == 0) {
                    Obf[(size_t)row * ldo + col] = f2bf(v);
                } else if (EPI == 1) {
                    float t = v * bscale + bshift;
                    t = 0.5f * t * (1.0f + erff(t * 0.70710678118654752f));
                    Obf[(size_t)row * ldo + col] = f2bf(t);
                } else if (EPI == 2) {
                    float t = v * bscale + bshift;
                    xf[(size_t)row * N + col] += gam * t;
                } else if (EPI == 3) {
                    xf[(size_t)row * N + col] += gam * v;
                } else if (EPI == 4) {
                    ofb[(size_t)row * N + col] = xf[(size_t)row * N + col] + gam * v;
                } else {
                    xf[(size_t)row * N + col] = xin[(size_t)row * N + col] + gam * v;
                }
            }
        }
    }
}

// ---------------------------------------------------------------- channel attention: per (b,h) Gram + norms + softmax
__global__ __launch_bounds__(256)
void attn_kernel(const u16* __restrict__ qkv, const float* __restrict__ temp,
                 float* __restrict__ attnb) {
    const int bh = blockIdx.x;
    const int b = bh >> 3, h = bh & 7;
    const int tid = threadIdx.x;
    __shared__ float qsf[64][48];
    __shared__ float ksf[64][48];
    __shared__ float qns[48], kns[48];
    __shared__ float S[48][49];

    float acc9[3][3];
#pragma unroll
    for (int i = 0; i < 3; ++i)
#pragma unroll
        for (int j = 0; j < 3; ++j) acc9[i][j] = 0.f;
    float qn2 = 0.f, kn2 = 0.f;

    const int qoff = h * 48;
    const int koff = 384 + h * 48;
    const int d0 = (tid >> 4) * 3;
    const int e0 = (tid & 15) * 3;

    for (int n0 = 0; n0 < 2304; n0 += 64) {
#pragma unroll
        for (int it = 0; it < 6; ++it) {
            int chunk = tid + it * 256;          // 0..1535: [q 768 | k 768] chunks of 4 bf16
            int mat = chunk >= 768 ? 1 : 0;
            int rem = chunk - mat * 768;
            int nn = rem / 12, u = rem - nn * 12;
            ushort4 raw = *(const ushort4*)(qkv + (size_t)(b * 2304 + n0 + nn) * 1152 +
                                            (mat ? koff : qoff) + u * 4);
            float4 f = make_float4(bf2f(raw.x), bf2f(raw.y), bf2f(raw.z), bf2f(raw.w));
            if (mat) *(float4*)&ksf[nn][u * 4] = f;
            else     *(float4*)&qsf[nn][u * 4] = f;
        }
        __syncthreads();
#pragma unroll 4
        for (int nn = 0; nn < 64; ++nn) {
            float q0 = qsf[nn][d0], q1 = qsf[nn][d0 + 1], q2 = qsf[nn][d0 + 2];
            float k0v = ksf[nn][e0], k1v = ksf[nn][e0 + 1], k2v = ksf[nn][e0 + 2];
            acc9[0][0] += q0 * k0v; acc9[0][1] += q0 * k1v; acc9[0][2] += q0 * k2v;
            acc9[1][0] += q1 * k0v; acc9[1][1] += q1 * k1v; acc9[1][2] += q1 * k2v;
            acc9[2][0] += q2 * k0v; acc9[2][1] += q2 * k1v; acc9[2][2] += q2 * k2v;
        }
        if (tid < 48) {
            for (int nn = 0; nn < 64; ++nn) { float q = qsf[nn][tid]; qn2 += q * q; }
        } else if (tid >= 128 && tid < 176) {
            int e = tid - 128;
            for (int nn = 0; nn < 64; ++nn) { float k = ksf[nn][e]; kn2 += k * k; }
        }
        __syncthreads();
    }

    if (tid < 48) qns[tid] = fmaxf(sqrtf(qn2), 1e-12f);
    else if (tid >= 128 && tid < 176) kns[tid - 128] = fmaxf(sqrtf(kn2), 1e-12f);
    __syncthreads();

    float tf = temp[h];
#pragma unroll
    for (int i = 0; i < 3; ++i)
#pragma unroll
        for (int j = 0; j < 3; ++j)
            S[d0 + i][e0 + j] = acc9[i][j] * tf / (qns[d0 + i] * kns[e0 + j]);
    __syncthreads();

    if (tid < 48) {
        float mx = -1e30f;
        for (int e = 0; e < 48; ++e) mx = fmaxf(mx, S[tid][e]);
        float sum = 0.f;
        for (int e = 0; e < 48; ++e) { float t = __expf(S[tid][e] - mx); S[tid][e] = t; sum += t; }
        float inv = 1.0f / sum;
        float* dst = attnb + ((size_t)bh * 48 + tid) * 48;
        for (int e = 0; e < 48; ++e) dst[e] = S[tid][e] * inv;
    }
}

// ---------------------------------------------------------------- out[b,n,h*48+d] = sum_e attn[b,h,d,e] * v[b,n,h*48+e]
__global__ __launch_bounds__(256)
void attnout_kernel(const u16* __restrict__ qkv, const float* __restrict__ attnb,
                    u16* __restrict__ z) {
    const int r0 = blockIdx.x * 64;
    const int h  = blockIdx.y;
    const int b  = r0 / 2304;
    const int tid = threadIdx.x;
    __shared__ float A[48][49];
    __shared__ float vsf[64][48];

    const float* asrc = attnb + (size_t)(b * 8 + h) * 2304;
    for (int i = tid; i < 2304; i += 256) {
        int d = i / 48, e = i - d * 48;
        A[d][e] = asrc[i];
    }
    const int voff = 768 + h * 48;
    for (int i = tid; i < 768; i += 256) {
        int nn = i / 12, u = i - nn * 12;
        ushort4 raw = *(const ushort4*)(qkv + (size_t)(r0 + nn) * 1152 + voff + u * 4);
        float4 f = make_float4(bf2f(raw.x), bf2f(raw.y), bf2f(raw.z), bf2f(raw.w));
        *(float4*)&vsf[nn][u * 4] = f;
    }
    __syncthreads();

    const int rr0 = (tid >> 4) * 4;
    const int d0  = (tid & 15) * 3;
    float acc[4][3];
#pragma unroll
    for (int r = 0; r < 4; ++r)
#pragma unroll
        for (int j = 0; j < 3; ++j) acc[r][j] = 0.f;

#pragma unroll 4
    for (int e = 0; e < 48; ++e) {
        float a0 = A[d0][e], a1 = A[d0 + 1][e], a2 = A[d0 + 2][e];
#pragma unroll
        for (int r = 0; r < 4; ++r) {
            float vv = vsf[rr0 + r][e];
            acc[r][0] += a0 * vv; acc[r][1] += a1 * vv; acc[r][2] += a2 * vv;
        }
    }
#pragma unroll
    for (int r = 0; r < 4; ++r)
#pragma unroll
        for (int j = 0; j < 3; ++j)
            z[(size_t)(r0 + rr0 + r) * 384 + h * 48 + d0 + j] = f2bf(acc[r][j]);
}

// ---------------------------------------------------------------- conv weight: f32 [O,C,3,3] -> bf16 [O, (dy*3+dx)*384 + c]
__global__ void reorder_w_kernel(const float* __restrict__ w, u16* __restrict__ wr, int n) {
    int i = blockIdx.x * blockDim.x + threadIdx.x;
    if (i < n) {
        int o = i / 3456, rem = i - o * 3456;
        int j = rem / 384, c = rem - j * 384;
        wr[i] = f2bf(w[(size_t)(o * 384 + c) * 9 + j]);
    }
}

// ---------------------------------------------------------------- (H, W) tail
__global__ void tail_kernel(const int* __restrict__ Hp, const int* __restrict__ Wp,
                            float* __restrict__ out, size_t base, int n_extra) {
    if (threadIdx.x == 0) {
        if (n_extra >= 1) out[base]     = (float)Hp[0];
        if (n_extra >= 2) out[base + 1] = (float)Wp[0];
    }
}

extern "C" void kernel_launch(void* const* d_in, const int* in_sizes, int n_in,
                              void* d_out, int out_size, void* d_ws, size_t ws_size,
                              hipStream_t stream) {
    const float* x      = (const float*)d_in[0];
    const float* ln1_g  = (const float*)d_in[1];
    const float* ln1_b  = (const float*)d_in[2];
    const float* w_qkv  = (const float*)d_in[3];
    const float* temp   = (const float*)d_in[4];
    const float* w_proj = (const float*)d_in[5];
    const float* gamma1 = (const float*)d_in[6];
    const float* ln2_g  = (const float*)d_in[7];
    const float* ln2_b  = (const float*)d_in[8];
    const float* mlp_w1 = (const float*)d_in[9];
    const float* bn1_g  = (const float*)d_in[10];
    const float* bn1_b  = (const float*)d_in[11];
    const float* bn1_m  = (const float*)d_in[12];
    const float* bn1_v  = (const float*)d_in[13];
    const float* mlp_w2 = (const float*)d_in[14];
    const float* bn2_g  = (const float*)d_in[15];
    const float* bn2_b  = (const float*)d_in[16];
    const float* bn2_m  = (const float*)d_in[17];
    const float* bn2_v  = (const float*)d_in[18];
    const float* gamma2 = (const float*)d_in[19];
    const float* ln3_g  = (const float*)d_in[20];
    const float* ln3_b  = (const float*)d_in[21];
    const float* pconv1 = (const float*)d_in[22];
    const float* pbn_g  = (const float*)d_in[23];
    const float* pbn_b  = (const float*)d_in[24];
    const float* pbn_m  = (const float*)d_in[25];
    const float* pbn_v  = (const float*)d_in[26];
    const float* pconv2 = (const float*)d_in[27];
    const float* gamma3 = (const float*)d_in[28];
    const int* Hp = (const int*)d_in[29];
    const int* Wp = (const int*)d_in[30];

    const int M = 36864, C = 384, C2 = 768, NQKV = 1152, KC = 3456;
    const size_t NBNC = (size_t)M * C;                 // 14,155,776

    const size_t SZ_XF  = NBNC * 4;                    //  f32 residual stream
    const size_t SZ_LN  = NBNC * 2;                    //  bf16 LN out / attn z
    const size_t SZ_BIG = (size_t)M * NQKV * 2;        //  bf16 qkv / mlp hidden / zero page
    const size_t SZ_P3  = SZ_LN;                       //  attnb + bf16 weights, later conv1 out
    const size_t SZ_W   = (size_t)C * KC * 2;
    if (ws_size < SZ_XF + SZ_LN + SZ_BIG + SZ_P3 + 2 * SZ_W) return;

    char* ws = (char*)d_ws;
    float* xf     = (float*)ws;
    u16*   lnbuf  = (u16*)(ws + SZ_XF);
    u16*   big    = (u16*)(ws + SZ_XF + SZ_LN);
    char*  p3     = ws + SZ_XF + SZ_LN + SZ_BIG;
    float* attnb  = (float*)p3;                                      // 1,179,648 B
    u16*   wqkvb  = (u16*)(p3 + 1179648);
    u16*   wprojb = (u16*)(p3 + 1179648 + 884736);
    u16*   w1b    = (u16*)(p3 + 1179648 + 884736 + 294912);
    u16*   w2b    = (u16*)(p3 + 1179648 + 884736 + 294912 + 589824);
    u16*   convbf = (u16*)p3;                                        // conv1 output (bf16, M*C)
    u16*   w1r    = (u16*)(p3 + SZ_P3);
    u16*   w2r    = (u16*)(p3 + SZ_P3 + SZ_W);
    u16*   zp     = big;                                             // 4 KB zero page (big is dead in block 3)

    const int n_extra = out_size - (int)NBNC;

    // weight conversions (f32 -> bf16)
    cvt_f2b_kernel<<<(NQKV * C / 4 + 255) / 256, 256, 0, stream>>>(w_qkv, wqkvb, NQKV * C / 4);
    cvt_f2b_kernel<<<(C * C / 4 + 255) / 256, 256, 0, stream>>>(w_proj, wprojb, C * C / 4);
    cvt_f2b_kernel<<<(C2 * C / 4 + 255) / 256, 256, 0, stream>>>(mlp_w1, w1b, C2 * C / 4);
    cvt_f2b_kernel<<<(C * C2 / 4 + 255) / 256, 256, 0, stream>>>(mlp_w2, w2b, C * C2 / 4);

    // --- attention block ---  (ln1 reads input x directly; no residual copy)
    ln_kernel<<<M, 64, 0, stream>>>(x, ln1_g, ln1_b, lnbuf);
    gemm_nt<0, 0><<<dim3(NQKV / 128, M / 128), 256, 0, stream>>>(
        lnbuf, wqkvb, M, NQKV, C, big, NQKV, nullptr, nullptr, nullptr,
        nullptr, nullptr, nullptr, nullptr, nullptr, nullptr);
    attn_kernel<<<128, 256, 0, stream>>>(big, temp, attnb);
    attnout_kernel<<<dim3(M / 64, 8), 256, 0, stream>>>(big, attnb, lnbuf);
    gemm_nt<0, 5><<<dim3(C / 128, M / 128), 256, 0, stream>>>(        // xf = x + gamma1 * proj
        lnbuf, wprojb, M, C, C, nullptr, 0, xf, nullptr, x,
        nullptr, nullptr, nullptr, nullptr, gamma1, nullptr);

    // --- ConvMlp block (1x1 convs + eval BN) ---
    ln_kernel<<<M, 64, 0, stream>>>(xf, ln2_g, ln2_b, lnbuf);
    gemm_nt<0, 1><<<dim3(C2 / 128, M / 128), 256, 0, stream>>>(
        lnbuf, w1b, M, C2, C, big, C2, nullptr, nullptr, nullptr,
        bn1_g, bn1_b, bn1_m, bn1_v, nullptr, nullptr);
    gemm_nt<0, 2><<<dim3(C / 128, M / 128), 256, 0, stream>>>(
        big, w2b, M, C, C2, nullptr, 0, xf, nullptr, nullptr,
        bn2_g, bn2_b, bn2_m, bn2_v, gamma2, nullptr);

    // --- projection block (3x3 conv -> BN -> GELU -> 3x3 conv), implicit im2col GEMMs ---
    ln_kernel<<<M, 64, 0, stream>>>(xf, ln3_g, ln3_b, lnbuf);
    reorder_w_kernel<<<(C * KC + 255) / 256, 256, 0, stream>>>(pconv1, w1r, C * KC);
    reorder_w_kernel<<<(C * KC + 255) / 256, 256, 0, stream>>>(pconv2, w2r, C * KC);
    zero_kernel<<<8, 256, 0, stream>>>(zp, 2048);      // 4 KB zero page for im2col halo
    gemm_nt<1, 1><<<dim3(C / 128, M / 128), 256, 0, stream>>>(
        lnbuf, w1r, M, C, KC, convbf, C, nullptr, nullptr, nullptr,
        pbn_g, pbn_b, pbn_m, pbn_v, nullptr, zp);
    gemm_nt<1, 4><<<dim3(C / 128, M / 128), 256, 0, stream>>>(
        convbf, w2r, M, C, KC, nullptr, 0, xf, (float*)d_out, nullptr,
        nullptr, nullptr, nullptr, nullptr, gamma3, zp);

    tail_kernel<<<1, 64, 0, stream>>>(Hp, Wp, (float*)d_out, NBNC, n_extra);
}